// Round 3
// baseline (490.460 us; speedup 1.0000x reference)
//
#include <hip/hip_runtime.h>

#define HIDDEN 1024
#define INTER  704
#define NEXP   32
#define TM     128

typedef __attribute__((ext_vector_type(8))) short bf16x8;
typedef __attribute__((ext_vector_type(4))) float f32x4;

__device__ __forceinline__ unsigned short f2bf(float f) {
    union { float f; unsigned u; } v; v.f = f;
    unsigned r = v.u + 0x7FFF + ((v.u >> 16) & 1);   // RNE
    return (unsigned short)(r >> 16);
}

__device__ __forceinline__ void load_lds16(const void* g, void* l) {
    __builtin_amdgcn_global_load_lds(
        (const __attribute__((address_space(1))) void*)g,
        (__attribute__((address_space(3))) void*)l, 16, 0, 0);
}

// map block m-index -> (expert, global row0, valid rows) over ragged groups
__device__ __forceinline__ bool map_tile(const int* s_tpe, int bm,
                                         int& row0, int& rows, int& e) {
    int start = 0, rem = bm;
    for (int i = 0; i < NEXP; ++i) {
        int g = s_tpe[i];
        int nt = (g + TM - 1) / TM;
        if (rem < nt) { row0 = start + rem * TM; rows = min(TM, g - rem * TM); e = i; return true; }
        rem -= nt; start += g;
    }
    return false;
}

// ---------------- prep: x fp32 -> bf16 (same layout) ----------------
__global__ void cvt_x(const float* __restrict__ x, unsigned short* __restrict__ xb, int n4) {
    int i = blockIdx.x * blockDim.x + threadIdx.x;
    for (; i < n4; i += gridDim.x * blockDim.x) {
        float4 v = ((const float4*)x)[i];
        uint2 o;
        o.x = (unsigned)f2bf(v.x) | ((unsigned)f2bf(v.y) << 16);
        o.y = (unsigned)f2bf(v.z) | ((unsigned)f2bf(v.w) << 16);
        ((uint2*)xb)[i] = o;
    }
}

// ---------------- prep: transpose+cvt both weights in one launch ----------------
// z < 32:  w1w3 [e][1024][1408] f32 -> w1t [e][j][1024] bf16, j = gate c -> 2c, up c -> 2c+1
// z >= 32: w2   [e][704][1024]  f32 -> w2t [e][n][704]  bf16
__global__ __launch_bounds__(256)
void transpose_cvt(const float* __restrict__ w1w3, unsigned short* __restrict__ w1t,
                   const float* __restrict__ w2, unsigned short* __restrict__ w2t)
{
    __shared__ unsigned short sT[64 * 72];
    int z = blockIdx.z;
    bool is1 = z < NEXP;
    int e = is1 ? z : z - NEXP;
    int R = is1 ? HIDDEN : INTER;         // input rows (k dim of output)
    int C = is1 ? 2 * INTER : HIDDEN;     // input cols (n dim of output)
    int c0 = blockIdx.x * 64, r0 = blockIdx.y * 64;
    if (c0 >= C || r0 >= R) return;
    const float* ip = (is1 ? w1w3 : w2) + (size_t)e * R * C;
    unsigned short* op = (is1 ? w1t : w2t) + (size_t)e * C * R;

    int t = threadIdx.x;
    {
        int r = t >> 2, cs = (t & 3) * 16;
        const float4* p = (const float4*)(ip + (size_t)(r0 + r) * C + c0 + cs);
        #pragma unroll
        for (int i = 0; i < 4; ++i) {
            float4 v = p[i];
            sT[(cs + 4 * i + 0) * 72 + r] = f2bf(v.x);
            sT[(cs + 4 * i + 1) * 72 + r] = f2bf(v.y);
            sT[(cs + 4 * i + 2) * 72 + r] = f2bf(v.z);
            sT[(cs + 4 * i + 3) * 72 + r] = f2bf(v.w);
        }
    }
    __syncthreads();
    {
        int c = t >> 2, rs = (t & 3) * 16;
        int cg = c0 + c;
        int j = is1 ? (cg < INTER ? 2 * cg : 2 * (cg - INTER) + 1) : cg;
        uint4 v0 = *(const uint4*)&sT[c * 72 + rs];
        uint4 v1 = *(const uint4*)&sT[c * 72 + rs + 8];
        uint4* q = (uint4*)(op + (size_t)j * R + r0 + rs);
        q[0] = v0; q[1] = v1;
    }
}

// ---------------- GEMM1 + SwiGLU (interleaved cols, 128x128, dbuf BK=32) ----------------
__global__ __launch_bounds__(256)
void gemm1_swiglu(const unsigned short* __restrict__ xb, const int* __restrict__ tpe,
                  const unsigned short* __restrict__ w1t, unsigned short* __restrict__ h)
{
    __shared__ int s_tpe[NEXP];
    __shared__ __align__(16) unsigned short sA[2][128 * 32];
    __shared__ __align__(16) unsigned short sB[2][128 * 32];

    int t = threadIdx.x;
    if (t < NEXP) s_tpe[t] = tpe[t];
    __syncthreads();

    int row0, rows, e;
    if (!map_tile(s_tpe, blockIdx.x, row0, rows, e)) return;
    int jb = blockIdx.y;   // 0..10, covers interleaved j = jb*128..+127

    int wv = t >> 6, lane = t & 63, l16 = lane & 15, quad = lane >> 4;
    int wr = wv >> 1, wc = wv & 1;
    int srow = lane >> 2, sblk = lane & 3;       // staging: 16 rows x 4 16B blocks
    int gblk = sblk ^ (srow & 3);                // XOR swizzle
    int xk = l16 & 3;

    const unsigned short* abase = xb + (size_t)row0 * HIDDEN;
    const unsigned short* bbase = w1t + ((size_t)e * 2 * INTER + (size_t)jb * 128) * HIDDEN;

    f32x4 acc[4][4];
    #pragma unroll
    for (int i = 0; i < 4; i++)
        #pragma unroll
        for (int j = 0; j < 4; j++) acc[i][j] = (f32x4)(0.f);

    auto stage = [&](int buf, int ko) {
        #pragma unroll
        for (int i = 0; i < 2; ++i) {
            int r = wv * 32 + i * 16 + srow;
            if (r < rows)
                load_lds16(abase + (size_t)r * HIDDEN + ko + gblk * 8,
                           &sA[buf][(wv * 32 + i * 16) * 32]);
        }
        #pragma unroll
        for (int i = 0; i < 2; ++i) {
            int jr = wv * 32 + i * 16 + srow;
            load_lds16(bbase + (size_t)jr * HIDDEN + ko + gblk * 8,
                       &sB[buf][(wv * 32 + i * 16) * 32]);
        }
    };
    auto compute = [&](int buf) {
        bf16x8 a[4], b[4];
        #pragma unroll
        for (int i = 0; i < 4; ++i) {
            a[i] = *(const bf16x8*)&sA[buf][(wr * 64 + i * 16 + l16) * 32 + ((quad ^ xk) << 3)];
            b[i] = *(const bf16x8*)&sB[buf][(wc * 64 + i * 16 + l16) * 32 + ((quad ^ xk) << 3)];
        }
        #pragma unroll
        for (int rt = 0; rt < 4; ++rt)
            #pragma unroll
            for (int ct = 0; ct < 4; ++ct)
                acc[rt][ct] = __builtin_amdgcn_mfma_f32_16x16x32_bf16(a[rt], b[ct], acc[rt][ct], 0, 0, 0);
    };

    stage(0, 0);
    __syncthreads();
    int buf = 0;
    for (int ko = 32; ko < HIDDEN; ko += 32) {
        stage(buf ^ 1, ko);   // loads fly while we compute
        compute(buf);
        __syncthreads();      // drains vmcnt after a full compute phase
        buf ^= 1;
    }
    compute(buf);

    // ---- epilogue: SwiGLU via shfl_xor(1), store h bf16 ----
    #pragma unroll
    for (int rt = 0; rt < 4; ++rt) {
        #pragma unroll
        for (int reg = 0; reg < 4; ++reg) {
            int rl = wr * 64 + rt * 16 + quad * 4 + reg;
            bool ok = rl < rows;
            size_t grow = (size_t)(row0 + rl);
            #pragma unroll
            for (int ct = 0; ct < 4; ++ct) {
                float own = acc[rt][ct][reg];
                float oth = __shfl_xor(own, 1, 64);
                float g = (l16 & 1) ? oth : own;
                float u = (l16 & 1) ? own : oth;
                float sv = g / (1.f + __expf(-g)) * u;
                if (ok && !(l16 & 1)) {
                    int c = (jb * 128 + wc * 64 + ct * 16 + l16) >> 1;
                    h[grow * INTER + c] = f2bf(sv);
                }
            }
        }
    }
}

// ---------------- GEMM2: out = h @ w2  (128x128, dbuf BK=32) ----------------
__global__ __launch_bounds__(256)
void gemm2(const unsigned short* __restrict__ h, const int* __restrict__ tpe,
           const unsigned short* __restrict__ w2t, float* __restrict__ out)
{
    __shared__ int s_tpe[NEXP];
    __shared__ __align__(16) unsigned short sA[2][128 * 32];
    __shared__ __align__(16) unsigned short sB[2][128 * 32];

    int t = threadIdx.x;
    if (t < NEXP) s_tpe[t] = tpe[t];
    __syncthreads();

    int row0, rows, e;
    if (!map_tile(s_tpe, blockIdx.x, row0, rows, e)) return;
    int nb = blockIdx.y;   // 0..7

    int wv = t >> 6, lane = t & 63, l16 = lane & 15, quad = lane >> 4;
    int wr = wv >> 1, wc = wv & 1;
    int srow = lane >> 2, sblk = lane & 3;
    int gblk = sblk ^ (srow & 3);
    int xk = l16 & 3;

    const unsigned short* abase = h + (size_t)row0 * INTER;
    const unsigned short* bbase = w2t + ((size_t)e * HIDDEN + (size_t)nb * 128) * INTER;

    f32x4 acc[4][4];
    #pragma unroll
    for (int i = 0; i < 4; i++)
        #pragma unroll
        for (int j = 0; j < 4; j++) acc[i][j] = (f32x4)(0.f);

    auto stage = [&](int buf, int ko) {
        #pragma unroll
        for (int i = 0; i < 2; ++i) {
            int r = wv * 32 + i * 16 + srow;
            if (r < rows)
                load_lds16(abase + (size_t)r * INTER + ko + gblk * 8,
                           &sA[buf][(wv * 32 + i * 16) * 32]);
        }
        #pragma unroll
        for (int i = 0; i < 2; ++i) {
            int nr = wv * 32 + i * 16 + srow;
            load_lds16(bbase + (size_t)nr * INTER + ko + gblk * 8,
                       &sB[buf][(wv * 32 + i * 16) * 32]);
        }
    };
    auto compute = [&](int buf) {
        bf16x8 a[4], b[4];
        #pragma unroll
        for (int i = 0; i < 4; ++i) {
            a[i] = *(const bf16x8*)&sA[buf][(wr * 64 + i * 16 + l16) * 32 + ((quad ^ xk) << 3)];
            b[i] = *(const bf16x8*)&sB[buf][(wc * 64 + i * 16 + l16) * 32 + ((quad ^ xk) << 3)];
        }
        #pragma unroll
        for (int rt = 0; rt < 4; ++rt)
            #pragma unroll
            for (int ct = 0; ct < 4; ++ct)
                acc[rt][ct] = __builtin_amdgcn_mfma_f32_16x16x32_bf16(a[rt], b[ct], acc[rt][ct], 0, 0, 0);
    };

    stage(0, 0);
    __syncthreads();
    int buf = 0;
    for (int ko = 32; ko < INTER; ko += 32) {   // 22 iters
        stage(buf ^ 1, ko);
        compute(buf);
        __syncthreads();
        buf ^= 1;
    }
    compute(buf);

    #pragma unroll
    for (int rt = 0; rt < 4; ++rt) {
        #pragma unroll
        for (int reg = 0; reg < 4; ++reg) {
            int rl = wr * 64 + rt * 16 + quad * 4 + reg;
            if (rl < rows) {
                size_t grow = (size_t)(row0 + rl);
                #pragma unroll
                for (int ct = 0; ct < 4; ++ct)
                    out[grow * HIDDEN + nb * 128 + wc * 64 + ct * 16 + l16] = acc[rt][ct][reg];
            }
        }
    }
}

extern "C" void kernel_launch(void* const* d_in, const int* in_sizes, int n_in,
                              void* d_out, int out_size, void* d_ws, size_t ws_size,
                              hipStream_t stream) {
    const float* x    = (const float*)d_in[0];
    const int*   tpe  = (const int*)d_in[1];
    const float* w1w3 = (const float*)d_in[2];
    const float* w2   = (const float*)d_in[3];
    float* out = (float*)d_out;

    // ws layout (bf16 elems): h | xb | w1t | w2t  (~167 MB total)
    unsigned short* h   = (unsigned short*)d_ws;                 // 8192*704
    unsigned short* xb  = h + (size_t)8192 * INTER;              // 8192*1024
    unsigned short* w1t = xb + (size_t)8192 * HIDDEN;            // 32*1408*1024
    unsigned short* w2t = w1t + (size_t)NEXP * 2 * INTER * HIDDEN; // 32*1024*704

    hipLaunchKernelGGL(cvt_x, dim3(1024), dim3(256), 0, stream, x, xb, 8192 * HIDDEN / 4);
    hipLaunchKernelGGL(transpose_cvt, dim3(22, 16, 2 * NEXP), dim3(256), 0, stream,
                       w1w3, w1t, w2, w2t);
    hipLaunchKernelGGL(gemm1_swiglu, dim3(96, 11), dim3(256), 0, stream, xb, tpe, w1t, h);
    hipLaunchKernelGGL(gemm2, dim3(96, 8), dim3(256), 0, stream, h, tpe, w2t, out);
}

// Round 4
// 429.835 us; speedup vs baseline: 1.1410x; 1.1410x over previous
//
#include <hip/hip_runtime.h>

#define HIDDEN 1024
#define INTER  704
#define NEXP   32
#define TM     128

typedef __attribute__((ext_vector_type(8))) short bf16x8;
typedef __attribute__((ext_vector_type(4))) float f32x4;

__device__ __forceinline__ unsigned short f2bf(float f) {
    union { float f; unsigned u; } v; v.f = f;
    unsigned r = v.u + 0x7FFF + ((v.u >> 16) & 1);   // RNE
    return (unsigned short)(r >> 16);
}
__device__ __forceinline__ unsigned pkbf(float lo, float hi) {
    return (unsigned)f2bf(lo) | ((unsigned)f2bf(hi) << 16);
}
__device__ __forceinline__ float fcomp(const float4& v, int c) {
    return c == 0 ? v.x : c == 1 ? v.y : c == 2 ? v.z : v.w;
}

__device__ __forceinline__ void load_lds16(const void* g, void* l) {
    __builtin_amdgcn_global_load_lds(
        (const __attribute__((address_space(1))) void*)g,
        (__attribute__((address_space(3))) void*)l, 16, 0, 0);
}

// map block m-index -> (expert, global row0, valid rows) over ragged groups
__device__ __forceinline__ bool map_tile(const int* s_tpe, int bm,
                                         int& row0, int& rows, int& e) {
    int start = 0, rem = bm;
    for (int i = 0; i < NEXP; ++i) {
        int g = s_tpe[i];
        int nt = (g + TM - 1) / TM;
        if (rem < nt) { row0 = start + rem * TM; rows = min(TM, g - rem * TM); e = i; return true; }
        rem -= nt; start += g;
    }
    return false;
}

// ---------------- prep: x fp32 -> bf16 (same layout) ----------------
__global__ void cvt_x(const float* __restrict__ x, unsigned short* __restrict__ xb, int n4) {
    int i = blockIdx.x * blockDim.x + threadIdx.x;
    for (; i < n4; i += gridDim.x * blockDim.x) {
        float4 v = ((const float4*)x)[i];
        uint2 o;
        o.x = pkbf(v.x, v.y);
        o.y = pkbf(v.z, v.w);
        ((uint2*)xb)[i] = o;
    }
}

// ---------------- GEMM1 + SwiGLU: h = silu(x@w1) * (x@w3) ----------------
// A: xb [8192][1024] bf16 via global_load_lds.
// B: w1w3 [e][1024][1408] fp32, transposed+converted inline during staging.
// Local col c (0..127): c = 16g+2j+s -> global col s*704 + jb*64 + 8g + j
// (even c = gate, odd c = up; gate index = jb*64 + c/2).
__global__ __launch_bounds__(256, 2)
void gemm1_swiglu(const unsigned short* __restrict__ xb, const int* __restrict__ tpe,
                  const float* __restrict__ w1w3, unsigned short* __restrict__ h)
{
    __shared__ int s_tpe[NEXP];
    __shared__ __align__(16) unsigned short sA[2][128 * 32];  // [m][k], swizzle key m&3
    __shared__ __align__(16) unsigned short sB[2][128 * 32];  // [c][k], swizzle key (c>>3)&3

    int t = threadIdx.x;
    if (t < NEXP) s_tpe[t] = tpe[t];
    __syncthreads();

    int row0, rows, e;
    if (!map_tile(s_tpe, blockIdx.x, row0, rows, e)) return;
    int jb = blockIdx.y;   // 0..10

    int wv = t >> 6, lane = t & 63, l16 = lane & 15, quad = lane >> 4;
    int wr = wv >> 1, wc = wv & 1;

    // A staging (global_load_lds): lane -> row lane>>2, block lane&3, key row&3
    int srow = lane >> 2, sblk = lane & 3;
    int gblk = sblk ^ (srow & 3);
    // B staging: thread -> span s, col-group g (8 cols), k-group kq (2 rows)
    int bs = t & 1, bg = (t >> 1) & 7, kq = t >> 4;   // kq 0..15
    int xk = l16 & 3;

    const unsigned short* abase = xb + (size_t)row0 * HIDDEN;
    const float* bbase = w1w3 + (size_t)e * HIDDEN * 1408 + bs * 704 + jb * 64 + bg * 8;

    f32x4 acc[4][4];
    #pragma unroll
    for (int i = 0; i < 4; i++)
        #pragma unroll
        for (int j = 0; j < 4; j++) acc[i][j] = (f32x4)(0.f);

    float4 bv[4];   // [i(row)][h(col-half)] flattened: bv[2*i+h]

    auto loadB = [&](int ko) {
        const float* p = bbase + (size_t)(ko + 2 * kq) * 1408;
        bv[0] = *(const float4*)(p);
        bv[1] = *(const float4*)(p + 4);
        bv[2] = *(const float4*)(p + 1408);
        bv[3] = *(const float4*)(p + 1408 + 4);
    };
    auto stageA = [&](int buf, int ko) {
        #pragma unroll
        for (int i = 0; i < 2; ++i) {
            int r = wv * 32 + i * 16 + srow;
            if (r < rows)
                load_lds16(abase + (size_t)r * HIDDEN + ko + gblk * 8,
                           &sA[buf][(wv * 32 + i * 16) * 32]);
        }
    };
    auto writeB = [&](int buf) {
        #pragma unroll
        for (int j = 0; j < 8; ++j) {
            float lo = (j < 4) ? fcomp(bv[0], j) : fcomp(bv[1], j - 4);
            float hi = (j < 4) ? fcomp(bv[2], j) : fcomp(bv[3], j - 4);
            int c = 16 * bg + 2 * j + bs;
            int key = (c >> 3) & 3;
            int idx = c * 32 + (((kq >> 2) ^ key) << 3) + ((kq & 3) << 1);
            *(unsigned*)&sB[buf][idx] = pkbf(lo, hi);
        }
    };
    auto compute = [&](int buf) {
        bf16x8 a[4], b[4];
        #pragma unroll
        for (int i = 0; i < 4; ++i) {
            a[i] = *(const bf16x8*)&sA[buf][(wr * 64 + i * 16 + l16) * 32 + ((quad ^ xk) << 3)];
            int c = wc * 64 + i * 16 + l16;
            b[i] = *(const bf16x8*)&sB[buf][c * 32 + ((quad ^ ((c >> 3) & 3)) << 3)];
        }
        #pragma unroll
        for (int rt = 0; rt < 4; ++rt)
            #pragma unroll
            for (int ct = 0; ct < 4; ++ct)
                acc[rt][ct] = __builtin_amdgcn_mfma_f32_16x16x32_bf16(a[rt], b[ct], acc[rt][ct], 0, 0, 0);
    };

    loadB(0);
    stageA(0, 0);
    writeB(0);
    __syncthreads();
    int buf = 0;
    for (int ko = 32; ko < HIDDEN; ko += 32) {   // 32 iters
        loadB(ko);            // next B -> regs (in flight during compute)
        stageA(buf ^ 1, ko);  // next A -> LDS DMA (in flight during compute)
        compute(buf);
        writeB(buf ^ 1);      // waits B loads, converts+transposes into LDS
        __syncthreads();
        buf ^= 1;
    }
    compute(buf);

    // ---- epilogue: SwiGLU via shfl_xor(1), store h bf16 ----
    #pragma unroll
    for (int rt = 0; rt < 4; ++rt) {
        #pragma unroll
        for (int reg = 0; reg < 4; ++reg) {
            int rl = wr * 64 + rt * 16 + quad * 4 + reg;
            bool ok = rl < rows;
            size_t grow = (size_t)(row0 + rl);
            #pragma unroll
            for (int ct = 0; ct < 4; ++ct) {
                float own = acc[rt][ct][reg];
                float oth = __shfl_xor(own, 1, 64);
                float g = (l16 & 1) ? oth : own;
                float u = (l16 & 1) ? own : oth;
                float sv = g / (1.f + __expf(-g)) * u;
                if (ok && !(l16 & 1)) {
                    int c = jb * 64 + ((wc * 64 + ct * 16 + l16) >> 1);
                    h[grow * INTER + c] = f2bf(sv);
                }
            }
        }
    }
}

// ---------------- GEMM2: out = h @ w2 ----------------
// A: h [8192][704] bf16 via global_load_lds.
// B: w2 [e][704][1024] fp32, transposed+converted inline. Local col c = 8g+j.
__global__ __launch_bounds__(256, 2)
void gemm2(const unsigned short* __restrict__ h, const int* __restrict__ tpe,
           const float* __restrict__ w2, float* __restrict__ out)
{
    __shared__ int s_tpe[NEXP];
    __shared__ __align__(16) unsigned short sA[2][128 * 32];
    __shared__ __align__(16) unsigned short sB[2][128 * 32];

    int t = threadIdx.x;
    if (t < NEXP) s_tpe[t] = tpe[t];
    __syncthreads();

    int row0, rows, e;
    if (!map_tile(s_tpe, blockIdx.x, row0, rows, e)) return;
    int nb = blockIdx.y;   // 0..7

    int wv = t >> 6, lane = t & 63, l16 = lane & 15, quad = lane >> 4;
    int wr = wv >> 1, wc = wv & 1;
    int srow = lane >> 2, sblk = lane & 3;
    int gblk = sblk ^ (srow & 3);
    int bg = t & 15, kq = t >> 4;   // 16 col-groups x 8 cols, kq 0..15 -> 2 rows
    int xk = l16 & 3;

    const unsigned short* abase = h + (size_t)row0 * INTER;
    const float* bbase = w2 + (size_t)e * INTER * HIDDEN + nb * 128 + bg * 8;

    f32x4 acc[4][4];
    #pragma unroll
    for (int i = 0; i < 4; i++)
        #pragma unroll
        for (int j = 0; j < 4; j++) acc[i][j] = (f32x4)(0.f);

    float4 bv[4];

    auto loadB = [&](int ko) {
        const float* p = bbase + (size_t)(ko + 2 * kq) * HIDDEN;
        bv[0] = *(const float4*)(p);
        bv[1] = *(const float4*)(p + 4);
        bv[2] = *(const float4*)(p + HIDDEN);
        bv[3] = *(const float4*)(p + HIDDEN + 4);
    };
    auto stageA = [&](int buf, int ko) {
        #pragma unroll
        for (int i = 0; i < 2; ++i) {
            int r = wv * 32 + i * 16 + srow;
            if (r < rows)
                load_lds16(abase + (size_t)r * INTER + ko + gblk * 8,
                           &sA[buf][(wv * 32 + i * 16) * 32]);
        }
    };
    auto writeB = [&](int buf) {
        #pragma unroll
        for (int j = 0; j < 8; ++j) {
            float lo = (j < 4) ? fcomp(bv[0], j) : fcomp(bv[1], j - 4);
            float hi = (j < 4) ? fcomp(bv[2], j) : fcomp(bv[3], j - 4);
            int c = 8 * bg + j;
            int key = (c >> 3) & 3;
            int idx = c * 32 + (((kq >> 2) ^ key) << 3) + ((kq & 3) << 1);
            *(unsigned*)&sB[buf][idx] = pkbf(lo, hi);
        }
    };
    auto compute = [&](int buf) {
        bf16x8 a[4], b[4];
        #pragma unroll
        for (int i = 0; i < 4; ++i) {
            a[i] = *(const bf16x8*)&sA[buf][(wr * 64 + i * 16 + l16) * 32 + ((quad ^ xk) << 3)];
            int c = wc * 64 + i * 16 + l16;
            b[i] = *(const bf16x8*)&sB[buf][c * 32 + ((quad ^ ((c >> 3) & 3)) << 3)];
        }
        #pragma unroll
        for (int rt = 0; rt < 4; ++rt)
            #pragma unroll
            for (int ct = 0; ct < 4; ++ct)
                acc[rt][ct] = __builtin_amdgcn_mfma_f32_16x16x32_bf16(a[rt], b[ct], acc[rt][ct], 0, 0, 0);
    };

    loadB(0);
    stageA(0, 0);
    writeB(0);
    __syncthreads();
    int buf = 0;
    for (int ko = 32; ko < INTER; ko += 32) {   // 22 iters
        loadB(ko);
        stageA(buf ^ 1, ko);
        compute(buf);
        writeB(buf ^ 1);
        __syncthreads();
        buf ^= 1;
    }
    compute(buf);

    #pragma unroll
    for (int rt = 0; rt < 4; ++rt) {
        #pragma unroll
        for (int reg = 0; reg < 4; ++reg) {
            int rl = wr * 64 + rt * 16 + quad * 4 + reg;
            if (rl < rows) {
                size_t grow = (size_t)(row0 + rl);
                #pragma unroll
                for (int ct = 0; ct < 4; ++ct)
                    out[grow * HIDDEN + nb * 128 + wc * 64 + ct * 16 + l16] = acc[rt][ct][reg];
            }
        }
    }
}

extern "C" void kernel_launch(void* const* d_in, const int* in_sizes, int n_in,
                              void* d_out, int out_size, void* d_ws, size_t ws_size,
                              hipStream_t stream) {
    const float* x    = (const float*)d_in[0];
    const int*   tpe  = (const int*)d_in[1];
    const float* w1w3 = (const float*)d_in[2];
    const float* w2   = (const float*)d_in[3];
    float* out = (float*)d_out;

    // ws (bf16 elems): h [8192*704] | xb [8192*1024]  (~27.5 MB)
    unsigned short* h  = (unsigned short*)d_ws;
    unsigned short* xb = h + (size_t)8192 * INTER;

    hipLaunchKernelGGL(cvt_x, dim3(1024), dim3(256), 0, stream, x, xb, 8192 * HIDDEN / 4);
    hipLaunchKernelGGL(gemm1_swiglu, dim3(96, 11), dim3(256), 0, stream, xb, tpe, w1w3, h);
    hipLaunchKernelGGL(gemm2, dim3(96, 8), dim3(256), 0, stream, h, tpe, w2, out);
}